// Round 6
// baseline (170.305 us; speedup 1.0000x reference)
//
#include <hip/hip_runtime.h>
#include <math.h>

#define EPSV 1e-6f
#define MINEIG 1e-4f

// ---------- small 3x3 helpers (all in registers) ----------

__device__ __forceinline__ void mm3(const float a[3][3], const float b[3][3], float c[3][3]) {
#pragma unroll
  for (int i = 0; i < 3; ++i)
#pragma unroll
    for (int j = 0; j < 3; ++j)
      c[i][j] = fmaf(a[i][0], b[0][j], fmaf(a[i][1], b[1][j], a[i][2] * b[2][j]));
}

__device__ __forceinline__ void inv3(const float a[3][3], float inv[3][3]) {
  float c00 = a[1][1] * a[2][2] - a[1][2] * a[2][1];
  float c01 = -(a[1][0] * a[2][2] - a[1][2] * a[2][0]);
  float c02 = a[1][0] * a[2][1] - a[1][1] * a[2][0];
  float det = a[0][0] * c00 + a[0][1] * c01 + a[0][2] * c02;
  float id = 1.0f / det;
  inv[0][0] = c00 * id;
  inv[0][1] = (a[0][2] * a[2][1] - a[0][1] * a[2][2]) * id;
  inv[0][2] = (a[0][1] * a[1][2] - a[0][2] * a[1][1]) * id;
  inv[1][0] = c01 * id;
  inv[1][1] = (a[0][0] * a[2][2] - a[0][2] * a[2][0]) * id;
  inv[1][2] = (a[0][2] * a[1][0] - a[0][0] * a[1][2]) * id;
  inv[2][0] = c02 * id;
  inv[2][1] = (a[0][1] * a[2][0] - a[0][0] * a[2][1]) * id;
  inv[2][2] = (a[0][0] * a[1][1] - a[0][1] * a[1][0]) * id;
}

// Matches reference _expm: scale by 2^-6, 12-term Taylor, 6 squarings.
__device__ void expm3(const float A[3][3], float E[3][3]) {
  float As[3][3], term[3][3], tmp[3][3];
#pragma unroll
  for (int i = 0; i < 3; ++i)
#pragma unroll
    for (int j = 0; j < 3; ++j) {
      As[i][j] = A[i][j] * (1.0f / 64.0f);
      term[i][j] = As[i][j];
      E[i][j] = ((i == j) ? 1.0f : 0.0f) + As[i][j];
    }
  for (int k = 2; k <= 12; ++k) {
    mm3(term, As, tmp);
    float r = 1.0f / (float)k;
#pragma unroll
    for (int i = 0; i < 3; ++i)
#pragma unroll
      for (int j = 0; j < 3; ++j) {
        term[i][j] = tmp[i][j] * r;
        E[i][j] += term[i][j];
      }
  }
  for (int s = 0; s < 6; ++s) {
    mm3(E, E, tmp);
#pragma unroll
    for (int i = 0; i < 3; ++i)
#pragma unroll
      for (int j = 0; j < 3; ++j) E[i][j] = tmp[i][j];
  }
}

// Direct Jacobi rotation in plane (P,Q), RI = remaining index.
template <int P, int Q, int RI>
__device__ __forceinline__ void jrot(float A[3][3], float V[3][3]) {
  float apq = A[P][Q];
  if (fabsf(apq) < 1e-20f) return;
  float theta = (A[Q][Q] - A[P][P]) / (2.0f * apq);
  float t = copysignf(1.0f, theta) / (fabsf(theta) + sqrtf(fmaf(theta, theta, 1.0f)));
  float c = 1.0f / sqrtf(fmaf(t, t, 1.0f));
  float s = t * c;
  A[P][P] = A[P][P] - t * apq;
  A[Q][Q] = A[Q][Q] + t * apq;
  A[P][Q] = 0.f; A[Q][P] = 0.f;
  float arp = A[RI][P], arq = A[RI][Q];
  float nrp = c * arp - s * arq;
  float nrq = s * arp + c * arq;
  A[RI][P] = nrp; A[P][RI] = nrp;
  A[RI][Q] = nrq; A[Q][RI] = nrq;
#pragma unroll
  for (int i = 0; i < 3; ++i) {
    float vip = V[i][P], viq = V[i][Q];
    V[i][P] = c * vip - s * viq;
    V[i][Q] = s * vip + c * viq;
  }
}

__device__ __forceinline__ bool finitef(float x) {
  return !(isnan(x) || isinf(x));
}

// ---------- kernel A: prep + colsum partials (float4) + lo moments ----------
// Three independent wave-uniform block roles fused into one dispatch.

__global__ void stageA_kernel(const float* __restrict__ Sp, const float* __restrict__ Sq,
                              const float* __restrict__ phi, const float* __restrict__ gen,
                              const float* __restrict__ beta, const float* __restrict__ mu,
                              const float* __restrict__ W,
                              float* __restrict__ Lp, float* __restrict__ Lq,
                              float* __restrict__ Rm, float* __restrict__ Ssoa,
                              float* __restrict__ pcs, float* __restrict__ Lo,
                              int N, int V) {
  int bid = blockIdx.x;
  int tid = threadIdx.x;
  int nPrep = N >> 8;                    // N/256
  int nCT = N >> 10;                     // column tiles of 1024
  int nColsum = (N >> 3) * nCT;          // (N/8) * (N/1024)
  if (bid < nPrep) {
    // ---- prep: Lambda_p, Lambda_q, R=expm(phi_mat), S=R^T Lq R (SoA) ----
    int i = bid * 256 + tid;
    float a[3][3], lp[3][3], lq[3][3];
#pragma unroll
    for (int k = 0; k < 3; ++k)
#pragma unroll
      for (int l = 0; l < 3; ++l)
        a[k][l] = Sp[i * 9 + k * 3 + l] + ((k == l) ? EPSV : 0.0f);
    inv3(a, lp);
#pragma unroll
    for (int k = 0; k < 3; ++k)
#pragma unroll
      for (int l = 0; l < 3; ++l)
        a[k][l] = Sq[i * 9 + k * 3 + l] + ((k == l) ? EPSV : 0.0f);
    inv3(a, lq);

    float p0 = phi[i * 3 + 0], p1 = phi[i * 3 + 1], p2 = phi[i * 3 + 2];
    float A[3][3];
#pragma unroll
    for (int k = 0; k < 3; ++k)
#pragma unroll
      for (int l = 0; l < 3; ++l)
        A[k][l] = p0 * gen[0 + k * 3 + l] + p1 * gen[9 + k * 3 + l] + p2 * gen[18 + k * 3 + l];
    float R[3][3];
    expm3(A, R);
    // phi_mat exactly skew -> expm(-phi_mat) == R^T bitwise.
    float Rt[3][3];
#pragma unroll
    for (int k = 0; k < 3; ++k)
#pragma unroll
      for (int l = 0; l < 3; ++l) Rt[k][l] = R[l][k];
    float t1[3][3], S[3][3];
    mm3(lq, R, t1);
    mm3(Rt, t1, S);
#pragma unroll
    for (int k = 0; k < 3; ++k)
#pragma unroll
      for (int l = 0; l < 3; ++l) {
        Lp[i * 9 + k * 3 + l] = lp[k][l];
        Lq[i * 9 + k * 3 + l] = lq[k][l];
        Rm[i * 9 + k * 3 + l] = R[k][l];
        Ssoa[(k * 3 + l) * N + i] = S[k][l];
      }
  } else if (bid < nPrep + nColsum) {
    // ---- colsum partial: 8 rows x 1024 cols per block, float4 loads ----
    int cb = bid - nPrep;
    int rs = cb / nCT;                   // row-split index, 0..N/8-1
    int ct = cb % nCT;
    int j4 = ct * 256 + tid;             // float4 column index
    const float4* bp = (const float4*)(beta + (size_t)(rs * 8) * N) + j4;
    float4 s = {0.f, 0.f, 0.f, 0.f};
#pragma unroll
    for (int r = 0; r < 8; ++r) {
      float4 b = bp[(size_t)r * (N >> 2)];
      s.x += b.x; s.y += b.y; s.z += b.z; s.w += b.w;
    }
    ((float4*)(pcs + (size_t)rs * N))[j4] = s;
  } else {
    // ---- lo: softmax moments over V, 4 n per block ----
    int n0 = (bid - nPrep - nColsum) * 4;
    float m[4][3];
#pragma unroll
    for (int j = 0; j < 4; ++j) {
      m[j][0] = mu[(n0 + j) * 3 + 0];
      m[j][1] = mu[(n0 + j) * 3 + 1];
      m[j][2] = mu[(n0 + j) * 3 + 2];
    }
    float acc[4][10];
#pragma unroll
    for (int j = 0; j < 4; ++j)
#pragma unroll
      for (int k = 0; k < 10; ++k) acc[j][k] = 0.f;

    const float4* W4 = (const float4*)W;
    for (int vb = tid; vb * 4 < V; vb += 256) {
      float4 f0 = W4[vb * 3 + 0];
      float4 f1 = W4[vb * 3 + 1];
      float4 f2 = W4[vb * 3 + 2];
      float wv[4][3] = {{f0.x, f0.y, f0.z}, {f0.w, f1.x, f1.y},
                        {f1.z, f1.w, f2.x}, {f2.y, f2.z, f2.w}};
#pragma unroll
      for (int c = 0; c < 4; ++c) {
        float w0 = wv[c][0], w1 = wv[c][1], w2 = wv[c][2];
        float p00 = w0 * w0, p01 = w0 * w1, p02 = w0 * w2;
        float p11 = w1 * w1, p12 = w1 * w2, p22 = w2 * w2;
#pragma unroll
        for (int j = 0; j < 4; ++j) {
          float l = fmaf(m[j][0], w0, fmaf(m[j][1], w1, m[j][2] * w2));
          float e = __expf(l);
          acc[j][0] += e;
          acc[j][1] = fmaf(e, w0, acc[j][1]);
          acc[j][2] = fmaf(e, w1, acc[j][2]);
          acc[j][3] = fmaf(e, w2, acc[j][3]);
          acc[j][4] = fmaf(e, p00, acc[j][4]);
          acc[j][5] = fmaf(e, p01, acc[j][5]);
          acc[j][6] = fmaf(e, p02, acc[j][6]);
          acc[j][7] = fmaf(e, p11, acc[j][7]);
          acc[j][8] = fmaf(e, p12, acc[j][8]);
          acc[j][9] = fmaf(e, p22, acc[j][9]);
        }
      }
    }

    __shared__ float sred[4][40];
#pragma unroll
    for (int j = 0; j < 4; ++j)
#pragma unroll
      for (int k = 0; k < 10; ++k) {
        float x = acc[j][k];
#pragma unroll
        for (int o = 32; o > 0; o >>= 1) x += __shfl_down(x, o, 64);
        if ((tid & 63) == 0) sred[tid >> 6][j * 10 + k] = x;
      }
    __syncthreads();
    if (tid < 4) {
      int j = tid;
      float tot[10];
#pragma unroll
      for (int k = 0; k < 10; ++k)
        tot[k] = sred[0][j * 10 + k] + sred[1][j * 10 + k] +
                 sred[2][j * 10 + k] + sred[3][j * 10 + k];
      float inv = 1.0f / tot[0];
      float mw0 = tot[1] * inv, mw1 = tot[2] * inv, mw2 = tot[3] * inv;
      float* o = Lo + (n0 + j) * 9;
      o[0] = tot[4] * inv - mw0 * mw0 + EPSV;
      float v01 = tot[5] * inv - mw0 * mw1;
      float v02 = tot[6] * inv - mw0 * mw2;
      o[1] = v01; o[3] = v01;
      o[2] = v02; o[6] = v02;
      o[4] = tot[7] * inv - mw1 * mw1 + EPSV;
      float v12 = tot[8] * inv - mw1 * mw2;
      o[5] = v12; o[7] = v12;
      o[8] = tot[9] * inv - mw2 * mw2 + EPSV;
    }
  }
}

// ---------- kernel B: T = beta @ S, one wave per output row, SoA S ----------

__global__ void bmm_kernel(const float* __restrict__ beta, const float* __restrict__ Ssoa,
                           float* __restrict__ T, int N) {
  int lane = threadIdx.x & 63;
  int w = threadIdx.x >> 6;
  int i = blockIdx.x * 4 + w;
  const float4* B4 = (const float4*)(beta + (size_t)i * N);
  float acc[9];
#pragma unroll
  for (int k = 0; k < 9; ++k) acc[k] = 0.f;

  for (int jt = 0; jt < N; jt += 256) {
    int q = (jt >> 2) + lane;          // float4 index, lane-contiguous
    float4 b = B4[q];
    float4 sv[9];
#pragma unroll
    for (int k = 0; k < 9; ++k) sv[k] = ((const float4*)(Ssoa + k * N))[q];
#pragma unroll
    for (int k = 0; k < 9; ++k) {
      acc[k] = fmaf(b.x, sv[k].x, acc[k]);
      acc[k] = fmaf(b.y, sv[k].y, acc[k]);
      acc[k] = fmaf(b.z, sv[k].z, acc[k]);
      acc[k] = fmaf(b.w, sv[k].w, acc[k]);
    }
  }
#pragma unroll
  for (int k = 0; k < 9; ++k) {
    float x = acc[k];
#pragma unroll
    for (int o = 32; o > 0; o >>= 1) x += __shfl_down(x, o, 64);
    if (lane == 0) T[i * 9 + k] = x;
  }
}

// ---------- kernel C: thread-per-n finalize: assemble M, Jacobi, outputs ----------

__global__ void finalize_kernel(const float* __restrict__ Lp, const float* __restrict__ Lq,
                                const float* __restrict__ Rm, const float* __restrict__ Lo,
                                const float* __restrict__ T, const float* __restrict__ pcs,
                                float* __restrict__ out, int N) {
  int i = blockIdx.x * blockDim.x + threadIdx.x;
  if (i >= N) return;

  // fold colsum partials: coalesced (fixed r -> consecutive i)
  float c = 0.f;
  int RS = N >> 3;
  for (int r = 0; r < RS; ++r) c += pcs[(size_t)r * N + i];

  float R[3][3], Tm[3][3], M[3][3];
#pragma unroll
  for (int k = 0; k < 3; ++k)
#pragma unroll
    for (int l = 0; l < 3; ++l) {
      R[k][l] = Rm[i * 9 + k * 3 + l];
      Tm[k][l] = T[i * 9 + k * 3 + l];
    }
  float t1[3][3], Rt[3][3], Min[3][3];
  mm3(R, Tm, t1);
#pragma unroll
  for (int k = 0; k < 3; ++k)
#pragma unroll
    for (int l = 0; l < 3; ++l) Rt[k][l] = R[l][k];
  mm3(t1, Rt, Min);
#pragma unroll
  for (int k = 0; k < 3; ++k)
#pragma unroll
    for (int l = 0; l < 3; ++l)
      M[k][l] = Lp[i * 9 + k * 3 + l] + Lo[i * 9 + k * 3 + l] + Min[k][l] +
                c * Lq[i * 9 + k * 3 + l];
#pragma unroll
  for (int k = 0; k < 3; ++k)
#pragma unroll
    for (int l = 0; l < 3; ++l) {
      if (l > k) {
        float v = 0.5f * (M[k][l] + M[l][k]);
        M[k][l] = v; M[l][k] = v;
      }
    }
#pragma unroll
  for (int k = 0; k < 3; ++k)
#pragma unroll
    for (int l = 0; l < 3; ++l)
      if (!finitef(M[k][l])) M[k][l] = (k == l) ? 1.0f : 0.0f;
  M[0][0] += MINEIG; M[1][1] += MINEIG; M[2][2] += MINEIG;

  float A[3][3], Vv[3][3] = {{1, 0, 0}, {0, 1, 0}, {0, 0, 1}};
#pragma unroll
  for (int k = 0; k < 3; ++k)
#pragma unroll
    for (int l = 0; l < 3; ++l) A[k][l] = M[k][l];
  for (int sweep = 0; sweep < 8; ++sweep) {
    jrot<0, 1, 2>(A, Vv);
    jrot<0, 2, 1>(A, Vv);
    jrot<1, 2, 0>(A, Vv);
  }
  float wc[3], wi[3];
#pragma unroll
  for (int k = 0; k < 3; ++k) {
    wc[k] = fmaxf(A[k][k], MINEIG);
    wi[k] = 1.0f / wc[k];
  }
#pragma unroll
  for (int k = 0; k < 3; ++k)
#pragma unroll
    for (int l = 0; l < 3; ++l) {
      float mpd = Vv[k][0] * wc[0] * Vv[l][0] + Vv[k][1] * wc[1] * Vv[l][1] +
                  Vv[k][2] * wc[2] * Vv[l][2];
      float mnv = Vv[k][0] * wi[0] * Vv[l][0] + Vv[k][1] * wi[1] * Vv[l][1] +
                  Vv[k][2] * wi[2] * Vv[l][2];
      out[i * 9 + k * 3 + l] = mpd;
      out[(size_t)N * 9 + i * 9 + k * 3 + l] = mnv;
    }
}

// ---------- launcher ----------

extern "C" void kernel_launch(void* const* d_in, const int* in_sizes, int n_in,
                              void* d_out, int out_size, void* d_ws, size_t ws_size,
                              hipStream_t stream) {
  const float* Sp = (const float*)d_in[0];
  const float* Sq = (const float*)d_in[1];
  const float* phi = (const float*)d_in[2];
  const float* beta = (const float*)d_in[3];
  const float* mu = (const float*)d_in[4];
  const float* W = (const float*)d_in[5];
  const float* gen = (const float*)d_in[6];
  float* out = (float*)d_out;

  const int N = in_sizes[2] / 3;   // phi is (B,N,3), B=1
  const int V = in_sizes[5] / 3;   // W_out is (V,3)

  float* ws = (float*)d_ws;
  float* Lp = ws;                        // N*9
  float* Lq = Lp + (size_t)N * 9;        // N*9
  float* Rm = Lq + (size_t)N * 9;        // N*9
  float* Ssoa = Rm + (size_t)N * 9;      // N*9 (SoA)
  float* Lo = Ssoa + (size_t)N * 9;      // N*9
  float* T = Lo + (size_t)N * 9;         // N*9
  float* pcs = T + (size_t)N * 9;        // (N/8)*N

  int nPrep = N / 256;
  int nColsum = (N / 8) * (N / 1024);
  int nLo = N / 4;
  stageA_kernel<<<nPrep + nColsum + nLo, 256, 0, stream>>>(
      Sp, Sq, phi, gen, beta, mu, W, Lp, Lq, Rm, Ssoa, pcs, Lo, N, V);
  bmm_kernel<<<N / 4, 256, 0, stream>>>(beta, Ssoa, T, N);
  finalize_kernel<<<N / 256, 256, 0, stream>>>(Lp, Lq, Rm, Lo, T, pcs, out, N);
}

// Round 7
// 112.919 us; speedup vs baseline: 1.5082x; 1.5082x over previous
//
#include <hip/hip_runtime.h>
#include <math.h>

#define EPSV 1e-6f
#define MINEIG 1e-4f

// ---------- small 3x3 helpers (all in registers) ----------

__device__ __forceinline__ void mm3(const float a[3][3], const float b[3][3], float c[3][3]) {
#pragma unroll
  for (int i = 0; i < 3; ++i)
#pragma unroll
    for (int j = 0; j < 3; ++j)
      c[i][j] = fmaf(a[i][0], b[0][j], fmaf(a[i][1], b[1][j], a[i][2] * b[2][j]));
}

__device__ __forceinline__ void inv3(const float a[3][3], float inv[3][3]) {
  float c00 = a[1][1] * a[2][2] - a[1][2] * a[2][1];
  float c01 = -(a[1][0] * a[2][2] - a[1][2] * a[2][0]);
  float c02 = a[1][0] * a[2][1] - a[1][1] * a[2][0];
  float det = a[0][0] * c00 + a[0][1] * c01 + a[0][2] * c02;
  float id = 1.0f / det;
  inv[0][0] = c00 * id;
  inv[0][1] = (a[0][2] * a[2][1] - a[0][1] * a[2][2]) * id;
  inv[0][2] = (a[0][1] * a[1][2] - a[0][2] * a[1][1]) * id;
  inv[1][0] = c01 * id;
  inv[1][1] = (a[0][0] * a[2][2] - a[0][2] * a[2][0]) * id;
  inv[1][2] = (a[0][2] * a[1][0] - a[0][0] * a[1][2]) * id;
  inv[2][0] = c02 * id;
  inv[2][1] = (a[0][1] * a[2][0] - a[0][0] * a[2][1]) * id;
  inv[2][2] = (a[0][0] * a[1][1] - a[0][1] * a[1][0]) * id;
}

// Matches reference _expm: scale by 2^-6, 12-term Taylor, 6 squarings.
__device__ void expm3(const float A[3][3], float E[3][3]) {
  float As[3][3], term[3][3], tmp[3][3];
#pragma unroll
  for (int i = 0; i < 3; ++i)
#pragma unroll
    for (int j = 0; j < 3; ++j) {
      As[i][j] = A[i][j] * (1.0f / 64.0f);
      term[i][j] = As[i][j];
      E[i][j] = ((i == j) ? 1.0f : 0.0f) + As[i][j];
    }
  for (int k = 2; k <= 12; ++k) {
    mm3(term, As, tmp);
    float r = 1.0f / (float)k;
#pragma unroll
    for (int i = 0; i < 3; ++i)
#pragma unroll
      for (int j = 0; j < 3; ++j) {
        term[i][j] = tmp[i][j] * r;
        E[i][j] += term[i][j];
      }
  }
  for (int s = 0; s < 6; ++s) {
    mm3(E, E, tmp);
#pragma unroll
    for (int i = 0; i < 3; ++i)
#pragma unroll
      for (int j = 0; j < 3; ++j) E[i][j] = tmp[i][j];
  }
}

// Direct Jacobi rotation in plane (P,Q), RI = remaining index.
template <int P, int Q, int RI>
__device__ __forceinline__ void jrot(float A[3][3], float V[3][3]) {
  float apq = A[P][Q];
  if (fabsf(apq) < 1e-20f) return;
  float theta = (A[Q][Q] - A[P][P]) / (2.0f * apq);
  float t = copysignf(1.0f, theta) / (fabsf(theta) + sqrtf(fmaf(theta, theta, 1.0f)));
  float c = 1.0f / sqrtf(fmaf(t, t, 1.0f));
  float s = t * c;
  A[P][P] = A[P][P] - t * apq;
  A[Q][Q] = A[Q][Q] + t * apq;
  A[P][Q] = 0.f; A[Q][P] = 0.f;
  float arp = A[RI][P], arq = A[RI][Q];
  float nrp = c * arp - s * arq;
  float nrq = s * arp + c * arq;
  A[RI][P] = nrp; A[P][RI] = nrp;
  A[RI][Q] = nrq; A[Q][RI] = nrq;
#pragma unroll
  for (int i = 0; i < 3; ++i) {
    float vip = V[i][P], viq = V[i][Q];
    V[i][P] = c * vip - s * viq;
    V[i][Q] = s * vip + c * viq;
  }
}

__device__ __forceinline__ bool finitef(float x) {
  return !(isnan(x) || isinf(x));
}

// ---------- kernel A: prep + colsum partials (RS=N/32) + lo moments ----------

__global__ void stageA_kernel(const float* __restrict__ Sp, const float* __restrict__ Sq,
                              const float* __restrict__ phi, const float* __restrict__ gen,
                              const float* __restrict__ beta, const float* __restrict__ mu,
                              const float* __restrict__ W,
                              float* __restrict__ Lp, float* __restrict__ Lq,
                              float* __restrict__ Rm, float* __restrict__ Ssoa,
                              float* __restrict__ pcs, float* __restrict__ Lo,
                              int N, int V) {
  int bid = blockIdx.x;
  int tid = threadIdx.x;
  int nPrep = N >> 8;                  // N/256
  int nCT = N >> 8;                    // column tiles of 256
  int nColsum = (N >> 5) * nCT;        // (N/32) * (N/256)
  if (bid < nPrep) {
    // ---- prep: Lambda_p, Lambda_q, R=expm(phi_mat), S=R^T Lq R (SoA) ----
    int i = bid * 256 + tid;
    float a[3][3], lp[3][3], lq[3][3];
#pragma unroll
    for (int k = 0; k < 3; ++k)
#pragma unroll
      for (int l = 0; l < 3; ++l)
        a[k][l] = Sp[i * 9 + k * 3 + l] + ((k == l) ? EPSV : 0.0f);
    inv3(a, lp);
#pragma unroll
    for (int k = 0; k < 3; ++k)
#pragma unroll
      for (int l = 0; l < 3; ++l)
        a[k][l] = Sq[i * 9 + k * 3 + l] + ((k == l) ? EPSV : 0.0f);
    inv3(a, lq);

    float p0 = phi[i * 3 + 0], p1 = phi[i * 3 + 1], p2 = phi[i * 3 + 2];
    float A[3][3];
#pragma unroll
    for (int k = 0; k < 3; ++k)
#pragma unroll
      for (int l = 0; l < 3; ++l)
        A[k][l] = p0 * gen[0 + k * 3 + l] + p1 * gen[9 + k * 3 + l] + p2 * gen[18 + k * 3 + l];
    float R[3][3];
    expm3(A, R);
    // phi_mat exactly skew -> expm(-phi_mat) == R^T bitwise.
    float Rt[3][3];
#pragma unroll
    for (int k = 0; k < 3; ++k)
#pragma unroll
      for (int l = 0; l < 3; ++l) Rt[k][l] = R[l][k];
    float t1[3][3], S[3][3];
    mm3(lq, R, t1);
    mm3(Rt, t1, S);
#pragma unroll
    for (int k = 0; k < 3; ++k)
#pragma unroll
      for (int l = 0; l < 3; ++l) {
        Lp[i * 9 + k * 3 + l] = lp[k][l];
        Lq[i * 9 + k * 3 + l] = lq[k][l];
        Rm[i * 9 + k * 3 + l] = R[k][l];
        Ssoa[(k * 3 + l) * N + i] = S[k][l];
      }
  } else if (bid < nPrep + nColsum) {
    // ---- colsum partial: 32 rows x 256 cols per block ----
    int cb = bid - nPrep;
    int rs = cb / nCT;                 // row-split index, 0..N/32-1
    int ct = cb % nCT;
    int j = ct * 256 + tid;
    const float* bp = beta + (size_t)(rs * 32) * N + j;
    float s = 0.f;
#pragma unroll
    for (int r = 0; r < 32; ++r) s += bp[(size_t)r * N];
    pcs[(size_t)rs * N + j] = s;
  } else {
    // ---- lo: softmax moments over V, 4 n per block ----
    int n0 = (bid - nPrep - nColsum) * 4;
    float m[4][3];
#pragma unroll
    for (int j = 0; j < 4; ++j) {
      m[j][0] = mu[(n0 + j) * 3 + 0];
      m[j][1] = mu[(n0 + j) * 3 + 1];
      m[j][2] = mu[(n0 + j) * 3 + 2];
    }
    float acc[4][10];
#pragma unroll
    for (int j = 0; j < 4; ++j)
#pragma unroll
      for (int k = 0; k < 10; ++k) acc[j][k] = 0.f;

    const float4* W4 = (const float4*)W;
    for (int vb = tid; vb * 4 < V; vb += 256) {
      float4 f0 = W4[vb * 3 + 0];
      float4 f1 = W4[vb * 3 + 1];
      float4 f2 = W4[vb * 3 + 2];
      float wv[4][3] = {{f0.x, f0.y, f0.z}, {f0.w, f1.x, f1.y},
                        {f1.z, f1.w, f2.x}, {f2.y, f2.z, f2.w}};
#pragma unroll
      for (int c = 0; c < 4; ++c) {
        float w0 = wv[c][0], w1 = wv[c][1], w2 = wv[c][2];
        float p00 = w0 * w0, p01 = w0 * w1, p02 = w0 * w2;
        float p11 = w1 * w1, p12 = w1 * w2, p22 = w2 * w2;
#pragma unroll
        for (int j = 0; j < 4; ++j) {
          float l = fmaf(m[j][0], w0, fmaf(m[j][1], w1, m[j][2] * w2));
          float e = __expf(l);
          acc[j][0] += e;
          acc[j][1] = fmaf(e, w0, acc[j][1]);
          acc[j][2] = fmaf(e, w1, acc[j][2]);
          acc[j][3] = fmaf(e, w2, acc[j][3]);
          acc[j][4] = fmaf(e, p00, acc[j][4]);
          acc[j][5] = fmaf(e, p01, acc[j][5]);
          acc[j][6] = fmaf(e, p02, acc[j][6]);
          acc[j][7] = fmaf(e, p11, acc[j][7]);
          acc[j][8] = fmaf(e, p12, acc[j][8]);
          acc[j][9] = fmaf(e, p22, acc[j][9]);
        }
      }
    }

    __shared__ float sred[4][40];
#pragma unroll
    for (int j = 0; j < 4; ++j)
#pragma unroll
      for (int k = 0; k < 10; ++k) {
        float x = acc[j][k];
#pragma unroll
        for (int o = 32; o > 0; o >>= 1) x += __shfl_down(x, o, 64);
        if ((tid & 63) == 0) sred[tid >> 6][j * 10 + k] = x;
      }
    __syncthreads();
    if (tid < 4) {
      int j = tid;
      float tot[10];
#pragma unroll
      for (int k = 0; k < 10; ++k)
        tot[k] = sred[0][j * 10 + k] + sred[1][j * 10 + k] +
                 sred[2][j * 10 + k] + sred[3][j * 10 + k];
      float inv = 1.0f / tot[0];
      float mw0 = tot[1] * inv, mw1 = tot[2] * inv, mw2 = tot[3] * inv;
      float* o = Lo + (n0 + j) * 9;
      o[0] = tot[4] * inv - mw0 * mw0 + EPSV;
      float v01 = tot[5] * inv - mw0 * mw1;
      float v02 = tot[6] * inv - mw0 * mw2;
      o[1] = v01; o[3] = v01;
      o[2] = v02; o[6] = v02;
      o[4] = tot[7] * inv - mw1 * mw1 + EPSV;
      float v12 = tot[8] * inv - mw1 * mw2;
      o[5] = v12; o[7] = v12;
      o[8] = tot[9] * inv - mw2 * mw2 + EPSV;
    }
  }
}

// ---------- kernel B: bmm rows (wave per row) + pcs fold (wave per n) ----------

__global__ void bmm_fold_kernel(const float* __restrict__ beta, const float* __restrict__ Ssoa,
                                const float* __restrict__ pcs, float* __restrict__ T,
                                float* __restrict__ cs, int N) {
  int lane = threadIdx.x & 63;
  int w = threadIdx.x >> 6;
  int nRow = N >> 2;                   // N/4 row blocks
  if ((int)blockIdx.x < nRow) {
    int i = blockIdx.x * 4 + w;
    const float4* B4 = (const float4*)(beta + (size_t)i * N);
    float acc[9];
#pragma unroll
    for (int k = 0; k < 9; ++k) acc[k] = 0.f;

    for (int jt = 0; jt < N; jt += 256) {
      int q = (jt >> 2) + lane;        // float4 index, lane-contiguous
      float4 b = B4[q];
      float4 sv[9];
#pragma unroll
      for (int k = 0; k < 9; ++k) sv[k] = ((const float4*)(Ssoa + k * N))[q];
#pragma unroll
      for (int k = 0; k < 9; ++k) {
        acc[k] = fmaf(b.x, sv[k].x, acc[k]);
        acc[k] = fmaf(b.y, sv[k].y, acc[k]);
        acc[k] = fmaf(b.z, sv[k].z, acc[k]);
        acc[k] = fmaf(b.w, sv[k].w, acc[k]);
      }
    }
#pragma unroll
    for (int k = 0; k < 9; ++k) {
      float x = acc[k];
#pragma unroll
      for (int o = 32; o > 0; o >>= 1) x += __shfl_down(x, o, 64);
      if (lane == 0) T[i * 9 + k] = x;
    }
  } else {
    // fold: wave per n, lane-parallel over the RS=N/32 partials
    int n = (blockIdx.x - nRow) * 4 + w;
    int RS = N >> 5;
    float x = 0.f;
    for (int r = lane; r < RS; r += 64) x += pcs[(size_t)r * N + n];
#pragma unroll
    for (int o = 32; o > 0; o >>= 1) x += __shfl_down(x, o, 64);
    if (lane == 0) cs[n] = x;
  }
}

// ---------- kernel C: thread-per-n finalize: assemble M, Jacobi, outputs ----------

__global__ void finalize_kernel(const float* __restrict__ Lp, const float* __restrict__ Lq,
                                const float* __restrict__ Rm, const float* __restrict__ Lo,
                                const float* __restrict__ T, const float* __restrict__ cs,
                                float* __restrict__ out, int N) {
  int i = blockIdx.x * blockDim.x + threadIdx.x;
  if (i >= N) return;

  float c = cs[i];
  float R[3][3], Tm[3][3], M[3][3];
#pragma unroll
  for (int k = 0; k < 3; ++k)
#pragma unroll
    for (int l = 0; l < 3; ++l) {
      R[k][l] = Rm[i * 9 + k * 3 + l];
      Tm[k][l] = T[i * 9 + k * 3 + l];
    }
  float t1[3][3], Rt[3][3], Min[3][3];
  mm3(R, Tm, t1);
#pragma unroll
  for (int k = 0; k < 3; ++k)
#pragma unroll
    for (int l = 0; l < 3; ++l) Rt[k][l] = R[l][k];
  mm3(t1, Rt, Min);
#pragma unroll
  for (int k = 0; k < 3; ++k)
#pragma unroll
    for (int l = 0; l < 3; ++l)
      M[k][l] = Lp[i * 9 + k * 3 + l] + Lo[i * 9 + k * 3 + l] + Min[k][l] +
                c * Lq[i * 9 + k * 3 + l];
#pragma unroll
  for (int k = 0; k < 3; ++k)
#pragma unroll
    for (int l = 0; l < 3; ++l) {
      if (l > k) {
        float v = 0.5f * (M[k][l] + M[l][k]);
        M[k][l] = v; M[l][k] = v;
      }
    }
#pragma unroll
  for (int k = 0; k < 3; ++k)
#pragma unroll
    for (int l = 0; l < 3; ++l)
      if (!finitef(M[k][l])) M[k][l] = (k == l) ? 1.0f : 0.0f;
  M[0][0] += MINEIG; M[1][1] += MINEIG; M[2][2] += MINEIG;

  float A[3][3], Vv[3][3] = {{1, 0, 0}, {0, 1, 0}, {0, 0, 1}};
#pragma unroll
  for (int k = 0; k < 3; ++k)
#pragma unroll
    for (int l = 0; l < 3; ++l) A[k][l] = M[k][l];
  for (int sweep = 0; sweep < 8; ++sweep) {
    jrot<0, 1, 2>(A, Vv);
    jrot<0, 2, 1>(A, Vv);
    jrot<1, 2, 0>(A, Vv);
  }
  float wc[3], wi[3];
#pragma unroll
  for (int k = 0; k < 3; ++k) {
    wc[k] = fmaxf(A[k][k], MINEIG);
    wi[k] = 1.0f / wc[k];
  }
#pragma unroll
  for (int k = 0; k < 3; ++k)
#pragma unroll
    for (int l = 0; l < 3; ++l) {
      float mpd = Vv[k][0] * wc[0] * Vv[l][0] + Vv[k][1] * wc[1] * Vv[l][1] +
                  Vv[k][2] * wc[2] * Vv[l][2];
      float mnv = Vv[k][0] * wi[0] * Vv[l][0] + Vv[k][1] * wi[1] * Vv[l][1] +
                  Vv[k][2] * wi[2] * Vv[l][2];
      out[i * 9 + k * 3 + l] = mpd;
      out[(size_t)N * 9 + i * 9 + k * 3 + l] = mnv;
    }
}

// ---------- launcher ----------

extern "C" void kernel_launch(void* const* d_in, const int* in_sizes, int n_in,
                              void* d_out, int out_size, void* d_ws, size_t ws_size,
                              hipStream_t stream) {
  const float* Sp = (const float*)d_in[0];
  const float* Sq = (const float*)d_in[1];
  const float* phi = (const float*)d_in[2];
  const float* beta = (const float*)d_in[3];
  const float* mu = (const float*)d_in[4];
  const float* W = (const float*)d_in[5];
  const float* gen = (const float*)d_in[6];
  float* out = (float*)d_out;

  const int N = in_sizes[2] / 3;   // phi is (B,N,3), B=1
  const int V = in_sizes[5] / 3;   // W_out is (V,3)

  float* ws = (float*)d_ws;
  float* Lp = ws;                        // N*9
  float* Lq = Lp + (size_t)N * 9;        // N*9
  float* Rm = Lq + (size_t)N * 9;        // N*9
  float* Ssoa = Rm + (size_t)N * 9;      // N*9 (SoA)
  float* Lo = Ssoa + (size_t)N * 9;      // N*9
  float* T = Lo + (size_t)N * 9;         // N*9
  float* pcs = T + (size_t)N * 9;        // (N/32)*N
  float* cs = pcs + (size_t)(N / 32) * N; // N

  int nPrep = N / 256;
  int nColsum = (N / 32) * (N / 256);
  int nLo = N / 4;
  stageA_kernel<<<nPrep + nColsum + nLo, 256, 0, stream>>>(
      Sp, Sq, phi, gen, beta, mu, W, Lp, Lq, Rm, Ssoa, pcs, Lo, N, V);
  bmm_fold_kernel<<<N / 4 + N / 4, 256, 0, stream>>>(beta, Ssoa, pcs, T, cs, N);
  finalize_kernel<<<N / 64, 64, 0, stream>>>(Lp, Lq, Rm, Lo, T, cs, out, N);
}

// Round 8
// 111.639 us; speedup vs baseline: 1.5255x; 1.0115x over previous
//
#include <hip/hip_runtime.h>
#include <math.h>

#define EPSV 1e-6f
#define MINEIG 1e-4f

// ---------- small 3x3 helpers (all in registers) ----------

__device__ __forceinline__ void mm3(const float a[3][3], const float b[3][3], float c[3][3]) {
#pragma unroll
  for (int i = 0; i < 3; ++i)
#pragma unroll
    for (int j = 0; j < 3; ++j)
      c[i][j] = fmaf(a[i][0], b[0][j], fmaf(a[i][1], b[1][j], a[i][2] * b[2][j]));
}

__device__ __forceinline__ void inv3(const float a[3][3], float inv[3][3]) {
  float c00 = a[1][1] * a[2][2] - a[1][2] * a[2][1];
  float c01 = -(a[1][0] * a[2][2] - a[1][2] * a[2][0]);
  float c02 = a[1][0] * a[2][1] - a[1][1] * a[2][0];
  float det = a[0][0] * c00 + a[0][1] * c01 + a[0][2] * c02;
  float id = 1.0f / det;
  inv[0][0] = c00 * id;
  inv[0][1] = (a[0][2] * a[2][1] - a[0][1] * a[2][2]) * id;
  inv[0][2] = (a[0][1] * a[1][2] - a[0][2] * a[1][1]) * id;
  inv[1][0] = c01 * id;
  inv[1][1] = (a[0][0] * a[2][2] - a[0][2] * a[2][0]) * id;
  inv[1][2] = (a[0][2] * a[1][0] - a[0][0] * a[1][2]) * id;
  inv[2][0] = c02 * id;
  inv[2][1] = (a[0][1] * a[2][0] - a[0][0] * a[2][1]) * id;
  inv[2][2] = (a[0][0] * a[1][1] - a[0][1] * a[1][0]) * id;
}

// Matches reference _expm: scale by 2^-6, 12-term Taylor, 6 squarings.
__device__ void expm3(const float A[3][3], float E[3][3]) {
  float As[3][3], term[3][3], tmp[3][3];
#pragma unroll
  for (int i = 0; i < 3; ++i)
#pragma unroll
    for (int j = 0; j < 3; ++j) {
      As[i][j] = A[i][j] * (1.0f / 64.0f);
      term[i][j] = As[i][j];
      E[i][j] = ((i == j) ? 1.0f : 0.0f) + As[i][j];
    }
  for (int k = 2; k <= 12; ++k) {
    mm3(term, As, tmp);
    float r = 1.0f / (float)k;
#pragma unroll
    for (int i = 0; i < 3; ++i)
#pragma unroll
      for (int j = 0; j < 3; ++j) {
        term[i][j] = tmp[i][j] * r;
        E[i][j] += term[i][j];
      }
  }
  for (int s = 0; s < 6; ++s) {
    mm3(E, E, tmp);
#pragma unroll
    for (int i = 0; i < 3; ++i)
#pragma unroll
      for (int j = 0; j < 3; ++j) E[i][j] = tmp[i][j];
  }
}

// Direct Jacobi rotation in plane (P,Q), RI = remaining index.
template <int P, int Q, int RI>
__device__ __forceinline__ void jrot(float A[3][3], float V[3][3]) {
  float apq = A[P][Q];
  if (fabsf(apq) < 1e-20f) return;
  float theta = (A[Q][Q] - A[P][P]) / (2.0f * apq);
  float t = copysignf(1.0f, theta) / (fabsf(theta) + sqrtf(fmaf(theta, theta, 1.0f)));
  float c = 1.0f / sqrtf(fmaf(t, t, 1.0f));
  float s = t * c;
  A[P][P] = A[P][P] - t * apq;
  A[Q][Q] = A[Q][Q] + t * apq;
  A[P][Q] = 0.f; A[Q][P] = 0.f;
  float arp = A[RI][P], arq = A[RI][Q];
  float nrp = c * arp - s * arq;
  float nrq = s * arp + c * arq;
  A[RI][P] = nrp; A[P][RI] = nrp;
  A[RI][Q] = nrq; A[Q][RI] = nrq;
#pragma unroll
  for (int i = 0; i < 3; ++i) {
    float vip = V[i][P], viq = V[i][Q];
    V[i][P] = c * vip - s * viq;
    V[i][Q] = s * vip + c * viq;
  }
}

__device__ __forceinline__ bool finitef(float x) {
  return !(isnan(x) || isinf(x));
}

// ---------- kernel A: prep + colsum partials (RS=N/32) + lo moments ----------
// Three independent wave-uniform block roles fused into one dispatch.

__global__ void stageA_kernel(const float* __restrict__ Sp, const float* __restrict__ Sq,
                              const float* __restrict__ phi, const float* __restrict__ gen,
                              const float* __restrict__ beta, const float* __restrict__ mu,
                              const float* __restrict__ W,
                              float* __restrict__ Lp, float* __restrict__ Lq,
                              float* __restrict__ Rm, float* __restrict__ Ssoa,
                              float* __restrict__ pcs, float* __restrict__ Lo,
                              int N, int V) {
  int bid = blockIdx.x;
  int tid = threadIdx.x;
  int nPrep = N >> 8;                  // N/256
  int nCT = N >> 8;                    // column tiles of 256
  int nColsum = (N >> 5) * nCT;        // (N/32) * (N/256)
  if (bid < nPrep) {
    // ---- prep: Lambda_p, Lambda_q, R=expm(phi_mat), S=R^T Lq R (SoA) ----
    int i = bid * 256 + tid;
    float a[3][3], lp[3][3], lq[3][3];
#pragma unroll
    for (int k = 0; k < 3; ++k)
#pragma unroll
      for (int l = 0; l < 3; ++l)
        a[k][l] = Sp[i * 9 + k * 3 + l] + ((k == l) ? EPSV : 0.0f);
    inv3(a, lp);
#pragma unroll
    for (int k = 0; k < 3; ++k)
#pragma unroll
      for (int l = 0; l < 3; ++l)
        a[k][l] = Sq[i * 9 + k * 3 + l] + ((k == l) ? EPSV : 0.0f);
    inv3(a, lq);

    float p0 = phi[i * 3 + 0], p1 = phi[i * 3 + 1], p2 = phi[i * 3 + 2];
    float A[3][3];
#pragma unroll
    for (int k = 0; k < 3; ++k)
#pragma unroll
      for (int l = 0; l < 3; ++l)
        A[k][l] = p0 * gen[0 + k * 3 + l] + p1 * gen[9 + k * 3 + l] + p2 * gen[18 + k * 3 + l];
    float R[3][3];
    expm3(A, R);
    // phi_mat exactly skew -> expm(-phi_mat) == R^T bitwise.
    float Rt[3][3];
#pragma unroll
    for (int k = 0; k < 3; ++k)
#pragma unroll
      for (int l = 0; l < 3; ++l) Rt[k][l] = R[l][k];
    float t1[3][3], S[3][3];
    mm3(lq, R, t1);
    mm3(Rt, t1, S);
#pragma unroll
    for (int k = 0; k < 3; ++k)
#pragma unroll
      for (int l = 0; l < 3; ++l) {
        Lp[i * 9 + k * 3 + l] = lp[k][l];
        Lq[i * 9 + k * 3 + l] = lq[k][l];
        Rm[i * 9 + k * 3 + l] = R[k][l];
        Ssoa[(k * 3 + l) * N + i] = S[k][l];
      }
  } else if (bid < nPrep + nColsum) {
    // ---- colsum partial: 32 rows x 256 cols per block ----
    int cb = bid - nPrep;
    int rs = cb / nCT;                 // row-split index, 0..N/32-1
    int ct = cb % nCT;
    int j = ct * 256 + tid;
    const float* bp = beta + (size_t)(rs * 32) * N + j;
    float s = 0.f;
#pragma unroll
    for (int r = 0; r < 32; ++r) s += bp[(size_t)r * N];
    pcs[(size_t)rs * N + j] = s;
  } else {
    // ---- lo: softmax moments over V, 4 n per block ----
    int n0 = (bid - nPrep - nColsum) * 4;
    float m[4][3];
#pragma unroll
    for (int j = 0; j < 4; ++j) {
      m[j][0] = mu[(n0 + j) * 3 + 0];
      m[j][1] = mu[(n0 + j) * 3 + 1];
      m[j][2] = mu[(n0 + j) * 3 + 2];
    }
    float acc[4][10];
#pragma unroll
    for (int j = 0; j < 4; ++j)
#pragma unroll
      for (int k = 0; k < 10; ++k) acc[j][k] = 0.f;

    const float4* W4 = (const float4*)W;
    for (int vb = tid; vb * 4 < V; vb += 256) {
      float4 f0 = W4[vb * 3 + 0];
      float4 f1 = W4[vb * 3 + 1];
      float4 f2 = W4[vb * 3 + 2];
      float wv[4][3] = {{f0.x, f0.y, f0.z}, {f0.w, f1.x, f1.y},
                        {f1.z, f1.w, f2.x}, {f2.y, f2.z, f2.w}};
#pragma unroll
      for (int c = 0; c < 4; ++c) {
        float w0 = wv[c][0], w1 = wv[c][1], w2 = wv[c][2];
        float p00 = w0 * w0, p01 = w0 * w1, p02 = w0 * w2;
        float p11 = w1 * w1, p12 = w1 * w2, p22 = w2 * w2;
#pragma unroll
        for (int j = 0; j < 4; ++j) {
          float l = fmaf(m[j][0], w0, fmaf(m[j][1], w1, m[j][2] * w2));
          float e = __expf(l);
          acc[j][0] += e;
          acc[j][1] = fmaf(e, w0, acc[j][1]);
          acc[j][2] = fmaf(e, w1, acc[j][2]);
          acc[j][3] = fmaf(e, w2, acc[j][3]);
          acc[j][4] = fmaf(e, p00, acc[j][4]);
          acc[j][5] = fmaf(e, p01, acc[j][5]);
          acc[j][6] = fmaf(e, p02, acc[j][6]);
          acc[j][7] = fmaf(e, p11, acc[j][7]);
          acc[j][8] = fmaf(e, p12, acc[j][8]);
          acc[j][9] = fmaf(e, p22, acc[j][9]);
        }
      }
    }

    __shared__ float sred[4][40];
#pragma unroll
    for (int j = 0; j < 4; ++j)
#pragma unroll
      for (int k = 0; k < 10; ++k) {
        float x = acc[j][k];
#pragma unroll
        for (int o = 32; o > 0; o >>= 1) x += __shfl_down(x, o, 64);
        if ((tid & 63) == 0) sred[tid >> 6][j * 10 + k] = x;
      }
    __syncthreads();
    if (tid < 4) {
      int j = tid;
      float tot[10];
#pragma unroll
      for (int k = 0; k < 10; ++k)
        tot[k] = sred[0][j * 10 + k] + sred[1][j * 10 + k] +
                 sred[2][j * 10 + k] + sred[3][j * 10 + k];
      float inv = 1.0f / tot[0];
      float mw0 = tot[1] * inv, mw1 = tot[2] * inv, mw2 = tot[3] * inv;
      float* o = Lo + (n0 + j) * 9;
      o[0] = tot[4] * inv - mw0 * mw0 + EPSV;
      float v01 = tot[5] * inv - mw0 * mw1;
      float v02 = tot[6] * inv - mw0 * mw2;
      o[1] = v01; o[3] = v01;
      o[2] = v02; o[6] = v02;
      o[4] = tot[7] * inv - mw1 * mw1 + EPSV;
      float v12 = tot[8] * inv - mw1 * mw2;
      o[5] = v12; o[7] = v12;
      o[8] = tot[9] * inv - mw2 * mw2 + EPSV;
    }
  }
}

// ---------- kernel B: bmm row (wave per row) + in-wave cs fold + finalize ----------
// 512 blocks x 256 threads, 1 output row per wave. After the T shfl-reduce the
// wave holds everything for row i; Jacobi runs redundantly on all 64 lanes
// (wave-uniform), lanes 0..8 store the output elements.

__global__ void bmm_finalize_kernel(const float* __restrict__ beta,
                                    const float* __restrict__ Ssoa,
                                    const float* __restrict__ pcs,
                                    const float* __restrict__ Lp,
                                    const float* __restrict__ Lq,
                                    const float* __restrict__ Rm,
                                    const float* __restrict__ Lo,
                                    float* __restrict__ out, int N) {
  int lane = threadIdx.x & 63;
  int w = threadIdx.x >> 6;
  int i = blockIdx.x * 4 + w;

  // ---- T row i = beta[i,:] @ S ----
  const float4* B4 = (const float4*)(beta + (size_t)i * N);
  float acc[9];
#pragma unroll
  for (int k = 0; k < 9; ++k) acc[k] = 0.f;

  for (int jt = 0; jt < N; jt += 256) {
    int q = (jt >> 2) + lane;          // float4 index, lane-contiguous
    float4 b = B4[q];
    float4 sv[9];
#pragma unroll
    for (int k = 0; k < 9; ++k) sv[k] = ((const float4*)(Ssoa + k * N))[q];
#pragma unroll
    for (int k = 0; k < 9; ++k) {
      acc[k] = fmaf(b.x, sv[k].x, acc[k]);
      acc[k] = fmaf(b.y, sv[k].y, acc[k]);
      acc[k] = fmaf(b.z, sv[k].z, acc[k]);
      acc[k] = fmaf(b.w, sv[k].w, acc[k]);
    }
  }
  float tv[9];
#pragma unroll
  for (int k = 0; k < 9; ++k) {
    float x = acc[k];
#pragma unroll
    for (int o = 32; o > 0; o >>= 1) x += __shfl_down(x, o, 64);
    tv[k] = __shfl(x, 0, 64);          // broadcast to all lanes
  }

  // ---- cs fold: RS = N/32 = 64 partials, exactly one per lane ----
  float cc = pcs[(size_t)lane * N + i];
#pragma unroll
  for (int o = 32; o > 0; o >>= 1) cc += __shfl_down(cc, o, 64);
  float c = __shfl(cc, 0, 64);

  // ---- finalize (redundant on all lanes, wave-uniform) ----
  float R[3][3], Tm[3][3], M[3][3];
#pragma unroll
  for (int k = 0; k < 3; ++k)
#pragma unroll
    for (int l = 0; l < 3; ++l) {
      R[k][l] = Rm[i * 9 + k * 3 + l];
      Tm[k][l] = tv[k * 3 + l];
    }
  float t1[3][3], Rt[3][3], Min[3][3];
  mm3(R, Tm, t1);
#pragma unroll
  for (int k = 0; k < 3; ++k)
#pragma unroll
    for (int l = 0; l < 3; ++l) Rt[k][l] = R[l][k];
  mm3(t1, Rt, Min);
#pragma unroll
  for (int k = 0; k < 3; ++k)
#pragma unroll
    for (int l = 0; l < 3; ++l)
      M[k][l] = Lp[i * 9 + k * 3 + l] + Lo[i * 9 + k * 3 + l] + Min[k][l] +
                c * Lq[i * 9 + k * 3 + l];
#pragma unroll
  for (int k = 0; k < 3; ++k)
#pragma unroll
    for (int l = 0; l < 3; ++l) {
      if (l > k) {
        float v = 0.5f * (M[k][l] + M[l][k]);
        M[k][l] = v; M[l][k] = v;
      }
    }
#pragma unroll
  for (int k = 0; k < 3; ++k)
#pragma unroll
    for (int l = 0; l < 3; ++l)
      if (!finitef(M[k][l])) M[k][l] = (k == l) ? 1.0f : 0.0f;
  M[0][0] += MINEIG; M[1][1] += MINEIG; M[2][2] += MINEIG;

  float A[3][3], Vv[3][3] = {{1, 0, 0}, {0, 1, 0}, {0, 0, 1}};
#pragma unroll
  for (int k = 0; k < 3; ++k)
#pragma unroll
    for (int l = 0; l < 3; ++l) A[k][l] = M[k][l];
  for (int sweep = 0; sweep < 8; ++sweep) {
    jrot<0, 1, 2>(A, Vv);
    jrot<0, 2, 1>(A, Vv);
    jrot<1, 2, 0>(A, Vv);
  }
  float wc[3], wi[3];
#pragma unroll
  for (int k = 0; k < 3; ++k) {
    wc[k] = fmaxf(A[k][k], MINEIG);
    wi[k] = 1.0f / wc[k];
  }
  // lanes 0..8 each store one element of M_pd and M_inv
  if (lane < 9) {
    int k = lane / 3, l = lane % 3;
    float mpd = Vv[k][0] * wc[0] * Vv[l][0] + Vv[k][1] * wc[1] * Vv[l][1] +
                Vv[k][2] * wc[2] * Vv[l][2];
    float mnv = Vv[k][0] * wi[0] * Vv[l][0] + Vv[k][1] * wi[1] * Vv[l][1] +
                Vv[k][2] * wi[2] * Vv[l][2];
    out[i * 9 + lane] = mpd;
    out[(size_t)N * 9 + i * 9 + lane] = mnv;
  }
}

// ---------- launcher ----------

extern "C" void kernel_launch(void* const* d_in, const int* in_sizes, int n_in,
                              void* d_out, int out_size, void* d_ws, size_t ws_size,
                              hipStream_t stream) {
  const float* Sp = (const float*)d_in[0];
  const float* Sq = (const float*)d_in[1];
  const float* phi = (const float*)d_in[2];
  const float* beta = (const float*)d_in[3];
  const float* mu = (const float*)d_in[4];
  const float* W = (const float*)d_in[5];
  const float* gen = (const float*)d_in[6];
  float* out = (float*)d_out;

  const int N = in_sizes[2] / 3;   // phi is (B,N,3), B=1
  const int V = in_sizes[5] / 3;   // W_out is (V,3)

  float* ws = (float*)d_ws;
  float* Lp = ws;                        // N*9
  float* Lq = Lp + (size_t)N * 9;        // N*9
  float* Rm = Lq + (size_t)N * 9;        // N*9
  float* Ssoa = Rm + (size_t)N * 9;      // N*9 (SoA)
  float* Lo = Ssoa + (size_t)N * 9;      // N*9
  float* pcs = Lo + (size_t)N * 9;       // (N/32)*N

  int nPrep = N / 256;
  int nColsum = (N / 32) * (N / 256);
  int nLo = N / 4;
  stageA_kernel<<<nPrep + nColsum + nLo, 256, 0, stream>>>(
      Sp, Sq, phi, gen, beta, mu, W, Lp, Lq, Rm, Ssoa, pcs, Lo, N, V);
  bmm_finalize_kernel<<<N / 4, 256, 0, stream>>>(beta, Ssoa, pcs, Lp, Lq, Rm, Lo, out, N);
}